// Round 1
// baseline (117.027 us; speedup 1.0000x reference)
//
#include <hip/hip_runtime.h>
#include <stdint.h>

// JAX RNG mode: 1 = threefry_partitionable (default True in modern JAX),
// 0 = legacy pairing mode. If adj output mismatches at ~0.1% density while w
// passes, flip this to 0.
#define RNG_PARTITIONABLE 1

namespace {

constexpr int kB = 16;
constexpr int kN = 1024;
constexpr int kF = 128;
constexpr int kHalf = kB * kN * kN;  // 16,777,216 == B*N*N; noise array is [2, B, N, N]

__device__ __forceinline__ uint32_t rotl32(uint32_t x, int r) {
  return (x << r) | (x >> (32 - r));
}

// JAX threefry2x32 with key = (0, 42)  [jax.random.key(42)]
__device__ __forceinline__ void tf2x32(uint32_t x0, uint32_t x1,
                                       uint32_t& o0, uint32_t& o1) {
  constexpr uint32_t ks0 = 0u;
  constexpr uint32_t ks1 = 42u;
  constexpr uint32_t ks2 = 0u ^ 42u ^ 0x1BD11BDAu;
  x0 += ks0; x1 += ks1;
#define TFR(r) { x0 += x1; x1 = rotl32(x1, (r)); x1 ^= x0; }
  TFR(13) TFR(15) TFR(26) TFR(6)
  x0 += ks1; x1 += ks2 + 1u;
  TFR(17) TFR(29) TFR(16) TFR(24)
  x0 += ks2; x1 += ks0 + 2u;
  TFR(13) TFR(15) TFR(26) TFR(6)
  x0 += ks0; x1 += ks1 + 3u;
  TFR(17) TFR(29) TFR(16) TFR(24)
  x0 += ks1; x1 += ks2 + 4u;
  TFR(13) TFR(15) TFR(26) TFR(6)
  x0 += ks2; x1 += ks0 + 5u;
#undef TFR
  o0 = x0; o1 = x1;
}

#if RNG_PARTITIONABLE
// partitionable mode: bits[idx] = o0 ^ o1 of threefry(key, (idx>>32, idx&0xffffffff))
__device__ __forceinline__ uint32_t random_bits_part(uint32_t idx) {
  uint32_t o0, o1;
  tf2x32(0u, idx, o0, o1);
  return o0 ^ o1;
}
#endif

// jax.random.uniform conversion: f in [0,1) from top-23 mantissa bits;
// u = max(1e-10f, f*(1.0f) + 1e-10f)   ((maxval-minval) rounds to exactly 1.0f)
__device__ __forceinline__ float bits_to_uniform(uint32_t bits) {
  float f = __uint_as_float((bits >> 9) | 0x3F800000u) - 1.0f;
  return fmaxf(1e-10f, f + 1e-10f);
}

// ---------------------------------------------------------------------------
// Kernel 1: probs[b,i] = clip(sigmoid(leaky_relu([left_b, nodes_bi] @ W1 + b1) @ W2 + b2))
// Tiled f32 GEMM: 512 blocks x 256 threads, each block does 32 rows (one b).
// Result scattered into out_w[(b*N + i)*N + nn_b] (read-before-write staging).
// ---------------------------------------------------------------------------
__global__ __launch_bounds__(256) void mlp_probs_kernel(
    const float* __restrict__ nodes, const int* __restrict__ num_nodes,
    const float* __restrict__ W1, const float* __restrict__ b1,
    const float* __restrict__ W2, const float* __restrict__ b2,
    float* __restrict__ out_w) {
  __shared__ float xs[32][256];   // 32 KiB: per-row input [left(128) | nodes_row(128)]
  __shared__ float bt[16][128];   // 8 KiB: W1 K-tile
  __shared__ float hs[32][128];   // 16 KiB: hidden activations
  __shared__ float h2[32][8];     // 1 KiB: second-layer partials

  const int blk = blockIdx.x;      // 512 blocks = 16 b * 32 row-chunks
  const int b = blk >> 5;
  const int i0 = (blk & 31) * 32;
  const int t = threadIdx.x;
  const int nn = num_nodes[b];
  const float* nb = nodes + (size_t)b * kN * kF;
  const float* leftp = nb + (size_t)nn * kF;

  // stage X tile [32 rows][256]
  for (int chunk = 0; chunk < 16; ++chunk) {
    int idx = chunk * 256 + t;   // 0..4095
    int r = idx >> 7;            // 0..31
    int c = idx & 127;
    xs[r][c] = leftp[c];
    xs[r][128 + c] = nb[(size_t)(i0 + r) * kF + c];
  }

  const int tx = t & 31;   // 4 cols each -> 128 cols
  const int ty = t >> 5;   // 4 rows each -> 32 rows
  float acc[4][4];
#pragma unroll
  for (int rr = 0; rr < 4; ++rr)
#pragma unroll
    for (int cc = 0; cc < 4; ++cc) acc[rr][cc] = 0.0f;

  for (int k0 = 0; k0 < 256; k0 += 16) {
    __syncthreads();  // xs ready (first iter) / bt consumers done (later iters)
#pragma unroll
    for (int qq = 0; qq < 8; ++qq) {
      int idx = qq * 256 + t;    // 0..2047
      int kk = idx >> 7;         // 0..15
      int c = idx & 127;
      bt[kk][c] = W1[(size_t)(k0 + kk) * kF + c];
    }
    __syncthreads();
#pragma unroll
    for (int kk = 0; kk < 16; ++kk) {
      float bv0 = bt[kk][4 * tx + 0];
      float bv1 = bt[kk][4 * tx + 1];
      float bv2 = bt[kk][4 * tx + 2];
      float bv3 = bt[kk][4 * tx + 3];
#pragma unroll
      for (int rr = 0; rr < 4; ++rr) {
        float xv = xs[4 * ty + rr][k0 + kk];
        acc[rr][0] = fmaf(xv, bv0, acc[rr][0]);
        acc[rr][1] = fmaf(xv, bv1, acc[rr][1]);
        acc[rr][2] = fmaf(xv, bv2, acc[rr][2]);
        acc[rr][3] = fmaf(xv, bv3, acc[rr][3]);
      }
    }
  }

  // bias + leaky_relu(0.01) -> hs
#pragma unroll
  for (int rr = 0; rr < 4; ++rr)
#pragma unroll
    for (int cc = 0; cc < 4; ++cc) {
      float v = acc[rr][cc] + b1[4 * tx + cc];
      hs[4 * ty + rr][4 * tx + cc] = (v >= 0.0f) ? v : 0.01f * v;
    }
  __syncthreads();

  // second layer: z = hs @ W2 + b2 ; 8 partial sums of 16 per row
  {
    const int r = t >> 3;  // 0..31
    const int q = t & 7;   // 0..7
    float s = 0.0f;
#pragma unroll
    for (int j = 0; j < 16; ++j) {
      int k = q * 16 + j;
      s = fmaf(hs[r][k], W2[k], s);
    }
    h2[r][q] = s;
  }
  __syncthreads();

  if (t < 32) {
    float z = 0.0f;
#pragma unroll
    for (int q = 0; q < 8; ++q) z += h2[t][q];
    z += b2[0];
    double p = 1.0 / (1.0 + exp(-(double)z));  // high-accuracy sigmoid
    float pc = fminf(fmaxf((float)p, 0.001f), 0.999f);
    // stage into out_w at [b][i][nn]; kernel 2's owning thread reads it back
    out_w[(size_t)((b << 10) + i0 + t) * kN + nn] = pc;
  }
}

// ---------------------------------------------------------------------------
// Kernel 2: per (b,i,j): w, gumbel-softmax hard sample. 4 elements per thread.
// ---------------------------------------------------------------------------
__global__ __launch_bounds__(256) void edge_sample_kernel(
    const float* __restrict__ weights, const int* __restrict__ num_nodes,
    float* __restrict__ out_adj, float* __restrict__ out_w) {
  const int tid = blockIdx.x * 256 + threadIdx.x;
  const int q0 = tid * 4;                 // grid sized exactly: q0 < kHalf
  const int b = q0 >> 20;                 // N*N = 2^20
  const int i = (q0 >> 10) & 1023;
  const int j0 = q0 & 1023;
  const int nn = num_nodes[b];
  const bool rowsel = (i < nn);
  const int rowbase = q0 - j0;            // (b*N + i)*N

  // p staged by kernel 1 at out_w[rowbase + nn]; only the thread whose quad
  // contains column nn needs it (it reads before it overwrites - same thread).
  float pv = 0.0f;
  if (rowsel && nn >= j0 && nn < j0 + 4) pv = out_w[rowbase + nn];

  const float4 wq = *reinterpret_cast<const float4*>(weights + q0);
  float wvals[4] = {wq.x, wq.y, wq.z, wq.w};
  float oa[4], ow[4];

#pragma unroll
  for (int ee = 0; ee < 4; ++ee) {
    const int j = j0 + ee;
    const float w = (rowsel && (j == nn)) ? pv : wvals[ee];
    // logits = log(clip([1-w, w], 0.001, 0.999))
    const float c1 = fminf(fmaxf(w, 0.001f), 0.999f);
    const float c0 = fminf(fmaxf(1.0f - w, 0.001f), 0.999f);

    const uint32_t idx0 = (uint32_t)(q0 + ee);          // noise[0,b,i,j]
    const uint32_t idx1 = idx0 + (uint32_t)kHalf;       // noise[1,b,i,j]
    float u0, u1;
#if RNG_PARTITIONABLE
    u0 = bits_to_uniform(random_bits_part(idx0));
    u1 = bits_to_uniform(random_bits_part(idx1));
#else
    {
      uint32_t o0, o1;
      tf2x32(idx0, idx1, o0, o1);  // legacy: pair (k, k+half) -> (bits[k], bits[k+half])
      u0 = bits_to_uniform(o0);
      u1 = bits_to_uniform(o1);
    }
#endif
    const float g0 = -logf(-logf(u0));
    const float g1 = -logf(-logf(u1));
    const float a0 = logf(c0) + g0;
    const float a1 = logf(c1) + g1;
    // softmax over the 2-vector, then argmax==1  (ties -> argmax 0)
    const float m = fmaxf(a0, a1);
    const float e0 = expf(a0 - m);
    const float e1 = expf(a1 - m);
    const float se = e0 + e1;
    const float y0 = e0 / se;
    const float y1 = e1 / se;
    oa[ee] = (y1 > y0) ? 1.0f : 0.0f;  // adj_out == hard1 (+/- 6e-8 residual)
    ow[ee] = w;
  }

  *reinterpret_cast<float4*>(out_adj + q0) = make_float4(oa[0], oa[1], oa[2], oa[3]);
  *reinterpret_cast<float4*>(out_w + q0) = make_float4(ow[0], ow[1], ow[2], ow[3]);
}

}  // namespace

extern "C" void kernel_launch(void* const* d_in, const int* in_sizes, int n_in,
                              void* d_out, int out_size, void* d_ws, size_t ws_size,
                              hipStream_t stream) {
  (void)in_sizes; (void)n_in; (void)d_ws; (void)ws_size; (void)out_size;
  const float* nodes = (const float*)d_in[0];
  // d_in[1] = adj (unused by reference)
  const float* weights = (const float*)d_in[2];
  const int* num_nodes = (const int*)d_in[3];
  // d_in[4] = B scalar (compile-time constant here)
  const float* W1 = (const float*)d_in[5];
  const float* b1 = (const float*)d_in[6];
  const float* W2 = (const float*)d_in[7];
  const float* b2 = (const float*)d_in[8];

  float* out_adj = (float*)d_out;
  float* out_w = out_adj + (size_t)kHalf;

  hipLaunchKernelGGL(mlp_probs_kernel, dim3(512), dim3(256), 0, stream,
                     nodes, num_nodes, W1, b1, W2, b2, out_w);
  hipLaunchKernelGGL(edge_sample_kernel, dim3(kHalf / 1024), dim3(256), 0, stream,
                     weights, num_nodes, out_adj, out_w);
}

// Round 6
// 91.213 us; speedup vs baseline: 1.2830x; 1.2830x over previous
//
#include <hip/hip_runtime.h>
#include <stdint.h>

// JAX RNG mode: threefry_partitionable (verified correct in round 1).
#define RNG_PARTITIONABLE 1

namespace {

constexpr int kB = 16;
constexpr int kN = 1024;
constexpr int kF = 128;
constexpr int kHalf = kB * kN * kN;  // 16,777,216 == B*N*N; noise array is [2, B, N, N]

__device__ __forceinline__ uint32_t rotl32(uint32_t x, int r) {
  return (x << r) | (x >> (32 - r));
}

// JAX threefry2x32 with key = (0, 42)  [jax.random.key(42)]
__device__ __forceinline__ void tf2x32(uint32_t x0, uint32_t x1,
                                       uint32_t& o0, uint32_t& o1) {
  constexpr uint32_t ks0 = 0u;
  constexpr uint32_t ks1 = 42u;
  constexpr uint32_t ks2 = 0u ^ 42u ^ 0x1BD11BDAu;
  x0 += ks0; x1 += ks1;
#define TFR(r) { x0 += x1; x1 = rotl32(x1, (r)); x1 ^= x0; }
  TFR(13) TFR(15) TFR(26) TFR(6)
  x0 += ks1; x1 += ks2 + 1u;
  TFR(17) TFR(29) TFR(16) TFR(24)
  x0 += ks2; x1 += ks0 + 2u;
  TFR(13) TFR(15) TFR(26) TFR(6)
  x0 += ks0; x1 += ks1 + 3u;
  TFR(17) TFR(29) TFR(16) TFR(24)
  x0 += ks1; x1 += ks2 + 4u;
  TFR(13) TFR(15) TFR(26) TFR(6)
  x0 += ks2; x1 += ks0 + 5u;
#undef TFR
  o0 = x0; o1 = x1;
}

// partitionable mode: bits[idx] = o0 ^ o1 of threefry(key, (idx>>32, idx&0xffffffff))
__device__ __forceinline__ uint32_t random_bits_part(uint32_t idx) {
  uint32_t o0, o1;
  tf2x32(0u, idx, o0, o1);
  return o0 ^ o1;
}

// jax.random.uniform conversion: f in [0,1) from top-23 mantissa bits;
// u = max(1e-10f, f + 1e-10f)   ((maxval-minval) rounds to exactly 1.0f)
__device__ __forceinline__ float bits_to_uniform(uint32_t bits) {
  float f = __uint_as_float((bits >> 9) | 0x3F800000u) - 1.0f;
  return fmaxf(1e-10f, f + 1e-10f);
}

// ---------------------------------------------------------------------------
// Kernel 1: probs[b,i] = clip(sigmoid(leaky_relu([left_b, nodes_bi] @ W1 + b1) @ W2 + b2))
// Tiled f32 GEMM: 512 blocks x 256 threads, each block does 32 rows (one b).
// Result scattered into out_w[(b*N + i)*N + nn_b] (read-before-write staging).
// ---------------------------------------------------------------------------
__global__ __launch_bounds__(256) void mlp_probs_kernel(
    const float* __restrict__ nodes, const int* __restrict__ num_nodes,
    const float* __restrict__ W1, const float* __restrict__ b1,
    const float* __restrict__ W2, const float* __restrict__ b2,
    float* __restrict__ out_w) {
  __shared__ float xs[32][256];   // 32 KiB: per-row input [left(128) | nodes_row(128)]
  __shared__ float bt[16][128];   // 8 KiB: W1 K-tile
  __shared__ float hs[32][128];   // 16 KiB: hidden activations
  __shared__ float h2[32][8];     // 1 KiB: second-layer partials

  const int blk = blockIdx.x;      // 512 blocks = 16 b * 32 row-chunks
  const int b = blk >> 5;
  const int i0 = (blk & 31) * 32;
  const int t = threadIdx.x;
  const int nn = num_nodes[b];
  const float* nb = nodes + (size_t)b * kN * kF;
  const float* leftp = nb + (size_t)nn * kF;

  // stage X tile [32 rows][256]
  for (int chunk = 0; chunk < 16; ++chunk) {
    int idx = chunk * 256 + t;   // 0..4095
    int r = idx >> 7;            // 0..31
    int c = idx & 127;
    xs[r][c] = leftp[c];
    xs[r][128 + c] = nb[(size_t)(i0 + r) * kF + c];
  }

  const int tx = t & 31;   // 4 cols each -> 128 cols
  const int ty = t >> 5;   // 4 rows each -> 32 rows
  float acc[4][4];
#pragma unroll
  for (int rr = 0; rr < 4; ++rr)
#pragma unroll
    for (int cc = 0; cc < 4; ++cc) acc[rr][cc] = 0.0f;

  for (int k0 = 0; k0 < 256; k0 += 16) {
    __syncthreads();  // xs ready (first iter) / bt consumers done (later iters)
#pragma unroll
    for (int qq = 0; qq < 8; ++qq) {
      int idx = qq * 256 + t;    // 0..2047
      int kk = idx >> 7;         // 0..15
      int c = idx & 127;
      bt[kk][c] = W1[(size_t)(k0 + kk) * kF + c];
    }
    __syncthreads();
#pragma unroll
    for (int kk = 0; kk < 16; ++kk) {
      float bv0 = bt[kk][4 * tx + 0];
      float bv1 = bt[kk][4 * tx + 1];
      float bv2 = bt[kk][4 * tx + 2];
      float bv3 = bt[kk][4 * tx + 3];
#pragma unroll
      for (int rr = 0; rr < 4; ++rr) {
        float xv = xs[4 * ty + rr][k0 + kk];
        acc[rr][0] = fmaf(xv, bv0, acc[rr][0]);
        acc[rr][1] = fmaf(xv, bv1, acc[rr][1]);
        acc[rr][2] = fmaf(xv, bv2, acc[rr][2]);
        acc[rr][3] = fmaf(xv, bv3, acc[rr][3]);
      }
    }
  }

  // bias + leaky_relu(0.01) -> hs
#pragma unroll
  for (int rr = 0; rr < 4; ++rr)
#pragma unroll
    for (int cc = 0; cc < 4; ++cc) {
      float v = acc[rr][cc] + b1[4 * tx + cc];
      hs[4 * ty + rr][4 * tx + cc] = (v >= 0.0f) ? v : 0.01f * v;
    }
  __syncthreads();

  // second layer: z = hs @ W2 + b2 ; 8 partial sums of 16 per row
  {
    const int r = t >> 3;  // 0..31
    const int q = t & 7;   // 0..7
    float s = 0.0f;
#pragma unroll
    for (int j = 0; j < 16; ++j) {
      int k = q * 16 + j;
      s = fmaf(hs[r][k], W2[k], s);
    }
    h2[r][q] = s;
  }
  __syncthreads();

  if (t < 32) {
    float z = 0.0f;
#pragma unroll
    for (int q = 0; q < 8; ++q) z += h2[t][q];
    z += b2[0];
    double p = 1.0 / (1.0 + exp(-(double)z));  // high-accuracy sigmoid
    float pc = fminf(fmaxf((float)p, 0.001f), 0.999f);
    // stage into out_w at [b][i][nn]; kernel 2's owning thread reads it back
    out_w[(size_t)((b << 10) + i0 + t) * kN + nn] = pc;
  }
}

// ---------------------------------------------------------------------------
// Kernel 2: per (b,i,j): w, gumbel-softmax hard sample. 4 elements per thread.
//
// Algebraic reduction (exact-math equivalent of the reference chain):
//   argmax(softmax(logits+g)) == 1
//     <=> log c1 - log L1 > log c0 - log L0      (L_k = -log u_k > 0)
//     <=> c1 * L0 > c0 * L1
// Ties map to class 0 on both paths (strict >). Saves 4 logf + 2 expf + div.
// ---------------------------------------------------------------------------
__global__ __launch_bounds__(256) void edge_sample_kernel(
    const float* __restrict__ weights, const int* __restrict__ num_nodes,
    float* __restrict__ out_adj, float* __restrict__ out_w) {
  const int tid = blockIdx.x * 256 + threadIdx.x;
  const int q0 = tid * 4;                 // grid sized exactly: q0 < kHalf
  const int b = q0 >> 20;                 // N*N = 2^20
  const int i = (q0 >> 10) & 1023;
  const int j0 = q0 & 1023;
  const int nn = num_nodes[b];
  const bool rowsel = (i < nn);
  const int rowbase = q0 - j0;            // (b*N + i)*N

  // p staged by kernel 1 at out_w[rowbase + nn]; only the thread whose quad
  // contains column nn needs it (it reads before it overwrites - same thread).
  float pv = 0.0f;
  if (rowsel && nn >= j0 && nn < j0 + 4) pv = out_w[rowbase + nn];

  const float4 wq = *reinterpret_cast<const float4*>(weights + q0);
  float wvals[4] = {wq.x, wq.y, wq.z, wq.w};
  float oa[4], ow[4];

#pragma unroll
  for (int ee = 0; ee < 4; ++ee) {
    const int j = j0 + ee;
    const float w = (rowsel && (j == nn)) ? pv : wvals[ee];
    // clip([1-w, w], 0.001, 0.999)
    const float c1 = fminf(fmaxf(w, 0.001f), 0.999f);
    const float c0 = fminf(fmaxf(1.0f - w, 0.001f), 0.999f);

    const uint32_t idx0 = (uint32_t)(q0 + ee);          // noise[0,b,i,j]
    const float u0 = bits_to_uniform(random_bits_part(idx0));
    const float u1 = bits_to_uniform(random_bits_part(idx0 + (uint32_t)kHalf));
    const float L0 = -logf(u0);   // Exp(1) variate for class 0
    const float L1 = -logf(u1);   // Exp(1) variate for class 1

    oa[ee] = (c1 * L0 > c0 * L1) ? 1.0f : 0.0f;  // adj_out == hard1
    ow[ee] = w;
  }

  *reinterpret_cast<float4*>(out_adj + q0) = make_float4(oa[0], oa[1], oa[2], oa[3]);
  *reinterpret_cast<float4*>(out_w + q0) = make_float4(ow[0], ow[1], ow[2], ow[3]);
}

}  // namespace

extern "C" void kernel_launch(void* const* d_in, const int* in_sizes, int n_in,
                              void* d_out, int out_size, void* d_ws, size_t ws_size,
                              hipStream_t stream) {
  (void)in_sizes; (void)n_in; (void)d_ws; (void)ws_size; (void)out_size;
  const float* nodes = (const float*)d_in[0];
  // d_in[1] = adj (unused by reference)
  const float* weights = (const float*)d_in[2];
  const int* num_nodes = (const int*)d_in[3];
  // d_in[4] = B scalar (compile-time constant here)
  const float* W1 = (const float*)d_in[5];
  const float* b1 = (const float*)d_in[6];
  const float* W2 = (const float*)d_in[7];
  const float* b2 = (const float*)d_in[8];

  float* out_adj = (float*)d_out;
  float* out_w = out_adj + (size_t)kHalf;

  hipLaunchKernelGGL(mlp_probs_kernel, dim3(512), dim3(256), 0, stream,
                     nodes, num_nodes, W1, b1, W2, b2, out_w);
  hipLaunchKernelGGL(edge_sample_kernel, dim3(kHalf / 1024), dim3(256), 0, stream,
                     weights, num_nodes, out_adj, out_w);
}